// Round 6
// baseline (31.197 us; speedup 1.0000x reference)
//
#include <hip/hip_runtime.h>

// ToChoices: out[b,h,w,s,c] = (shuffle_indices[b,s] ? reals : fakes)[b,h,w,c]
// reals/fakes (64,256,256,3) f32, shuffle_indices (64,2) int, out (64,256,256,2,3) f32.
//
// Structure (R5, 30.8us): LDS-stage a 1024-pixel tile per block so EVERY
// global load and store is lane-contiguous (lane i <-> base + i*16B). The
// 12B-granularity interleave permutation happens via LDS scalar reads.
//
// R6 change: nontemporal OUTPUT stores. Stores are now full contiguous 1KB
// bursts per wave op, so the R3 failure mode (nt + strided partials -> RMW)
// does not apply. Goal: stop the 100MB/replay write stream from allocating
// in L2/L3 and evicting the L3-resident inputs (observed 36MB/replay input
// re-fetch). Inputs stay cached -> HBM traffic ~= writes only.

typedef float f32x4 __attribute__((ext_vector_type(4)));

#define HW 65536                  // pixels per image
#define TILE_PIX 1024             // pixels per block-tile
#define TILES_PER_B (HW / TILE_PIX)   // 64
#define SRC_FLOATS (TILE_PIX * 3) // 3072 floats staged per source (12 KB)
#define OUT_FLOATS (TILE_PIX * 6) // 6144 floats out per tile (24 KB)

__global__ __launch_bounds__(256) void tochoices_kernel(
    const float* __restrict__ reals,
    const float* __restrict__ fakes,
    const int* __restrict__ idx,
    float* __restrict__ out)
{
    __shared__ __align__(16) float lds[SRC_FLOATS + 4 + SRC_FLOATS];
    float* ldsA = lds;
    float* ldsB = lds + SRC_FLOATS + 4;

    int blk  = blockIdx.x;
    int b    = blk >> 6;          // / TILES_PER_B
    int tile = blk & (TILES_PER_B - 1);
    int t    = threadIdx.x;

    int i0 = idx[b * 2 + 0];      // slot 0: 0 = fakes, 1 = reals
    int i1 = idx[b * 2 + 1];

    long inbase = (long)b * (HW * 3) + (long)tile * SRC_FLOATS;

    // ---- Phase 1: contiguous global -> LDS staging (3x float4 per thread) --
    const f32x4* pA = (const f32x4*)((i0 ? reals : fakes) + inbase);
    #pragma unroll
    for (int k = 0; k < 3; ++k)
        ((f32x4*)ldsA)[t + 256 * k] = pA[t + 256 * k];

    const float* B = ldsA;        // if both slots pick the same image, reuse A
    if (i1 != i0) {               // block-uniform branch
        const f32x4* pB = (const f32x4*)((i1 ? reals : fakes) + inbase);
        #pragma unroll
        for (int k = 0; k < 3; ++k)
            ((f32x4*)ldsB)[t + 256 * k] = pB[t + 256 * k];
        B = ldsB;
    }
    __syncthreads();

    // ---- Phase 2: permuted LDS reads -> contiguous nontemporal stores -----
    // Tile-local out float4 index g; pixel-pair h = g/3, r = g%3; components
    // (A = slot-0 source, B = slot-1 source, base 6h):
    //   r=0: A+0 A+1 A+2 B+0
    //   r=1: B+1 B+2 A+3 A+4
    //   r=2: A+5 B+3 B+4 B+5
    f32x4* o = (f32x4*)(out + (long)b * (HW * 6) + (long)tile * OUT_FLOATS);
    #pragma unroll
    for (int k = 0; k < 6; ++k) {
        int g = t + 256 * k;
        int h = g / 3;
        int r = g - 3 * h;        // g % 3
        const float* a6 = ldsA + 6 * h;
        const float* b6 = B    + 6 * h;

        const float* px = (r == 0) ? a6 + 0 : (r == 1) ? b6 + 1 : a6 + 5;
        const float* py = (r == 0) ? a6 + 1 : (r == 1) ? b6 + 2 : b6 + 3;
        const float* pz = (r == 0) ? a6 + 2 : (r == 1) ? a6 + 3 : b6 + 4;
        const float* pw = (r == 0) ? b6 + 0 : (r == 1) ? a6 + 4 : b6 + 5;

        f32x4 v;
        v.x = *px; v.y = *py; v.z = *pz; v.w = *pw;
        __builtin_nontemporal_store(v, o + g);   // contiguous 1KB/wave-op
    }
}

extern "C" void kernel_launch(void* const* d_in, const int* in_sizes, int n_in,
                              void* d_out, int out_size, void* d_ws, size_t ws_size,
                              hipStream_t stream) {
    const float* reals = (const float*)d_in[0];
    const float* fakes = (const float*)d_in[1];
    const int*   idx   = (const int*)d_in[2];
    float* out = (float*)d_out;

    const int grid = 64 * TILES_PER_B;   // 4096 blocks, one 1024-pixel tile each
    tochoices_kernel<<<grid, 256, 0, stream>>>(reals, fakes, idx, out);
}